// Round 12
// baseline (240.787 us; speedup 1.0000x reference)
//
#include <hip/hip_runtime.h>
#include <hip/hip_bf16.h>

typedef __bf16 bf16x8 __attribute__((ext_vector_type(8)));
typedef float f32x4 __attribute__((ext_vector_type(4)));
typedef float f32x2 __attribute__((ext_vector_type(2)));

#define D_FEAT 128
#define CHUNK 1024
#define NW 49344   // packed weight elements

__device__ __forceinline__ float bits_to_f(unsigned int u) {
    union { unsigned int i; float f; } c; c.i = u; return c.f;
}
__device__ __forceinline__ unsigned short f_to_bf16(float f) {
    __hip_bfloat16 h = (__hip_bfloat16)f;
    return *(unsigned short*)&h;
}
__device__ __forceinline__ float ld(const void* p, int is16, size_t i) {
    return is16 ? (float)((const __hip_bfloat16*)p)[i] : ((const float*)p)[i];
}
// pack 4 floats -> 4 fp8 e4m3 (bytes 0..3), HW RNE
__device__ __forceinline__ unsigned int pack4_fp8(float v0, float v1, float v2, float v3) {
    int w = __builtin_amdgcn_cvt_pk_fp8_f32(v0, v1, 0, false);
    w = __builtin_amdgcn_cvt_pk_fp8_f32(v2, v3, w, true);
    return (unsigned int)w;
}
// per-wave dtype probe (proven R5-R11)
__device__ __forceinline__ int wave_probe16(const void* p) {
    const unsigned short v = ((const unsigned short*)p)[(threadIdx.x & 63) * 2];
    int e = (v >> 7) & 0xFF;
    unsigned long long m = __ballot(e >= 100 && e <= 140);
    return (__popcll(m) >= 48) ? 1 : 0;
}

// ---------- setup: weight pack -> bf16 AND degree count, one dispatch ----------
__global__ void setup_kernel(const void* x,
                             const void* W1l, const void* b1, const void* W1r,
                             const void* W2l, const void* b2, const void* W2r,
                             const int* __restrict__ dst, int E,
                             unsigned short* __restrict__ wout, int* __restrict__ deg) {
    int i = blockIdx.x * blockDim.x + threadIdx.x;
    if (i < NW) {            // 771 full waves; no wave straddles the boundary
        int is16 = wave_probe16(x);
        const void* s; int base;
        if      (i < 16384) { s = W1l; base = 0; }
        else if (i < 32768) { s = W1r; base = 16384; }
        else if (i < 40960) { s = W2l; base = 32768; }
        else if (i < 49152) { s = W2r; base = 40960; }
        else if (i < 49280) { s = b1;  base = 49152; }
        else                { s = b2;  base = 49280; }
        wout[i] = f_to_bf16(ld(s, is16, i - base));
    } else {
        int j = i - NW;
        if (j < E) atomicAdd(&deg[dst[j]], 1);
    }
}

// ---------- scan phase 1: per-chunk padded-degree sums ----------
__global__ void scan1_kernel(const int* __restrict__ deg, int* __restrict__ bsum, int n) {
    __shared__ int ws[4];
    const int lane = threadIdx.x & 63, wv = threadIdx.x >> 6;
    int i0 = blockIdx.x * CHUNK + threadIdx.x * 4;
    int s = 0;
    #pragma unroll
    for (int j = 0; j < 4; ++j)
        if (i0 + j < n) { int d = deg[i0 + j]; s += (d + 3) & ~3; }
    #pragma unroll
    for (int d = 1; d < 64; d <<= 1) s += __shfl_xor(s, d, 64);
    if (lane == 0) ws[wv] = s;
    __syncthreads();
    if (threadIdx.x == 0) bsum[blockIdx.x] = ws[0] + ws[1] + ws[2] + ws[3];
}

// ---------- scan phase 2 (merged scan2+scan3+pad writes) ----------
__global__ void scan3_kernel(const int* __restrict__ deg, const int* __restrict__ bsum,
                             int nb, int* __restrict__ off, int* __restrict__ cursor,
                             int* __restrict__ esrc, int n) {
    __shared__ int ws[4];
    const int lane = threadIdx.x & 63, wv = threadIdx.x >> 6;
    int bv = (lane < nb) ? bsum[lane] : 0;
    int bsc = bv;
    #pragma unroll
    for (int s = 1; s < 64; s <<= 1) {
        int t = __shfl_up(bsc, s, 64);
        if (lane >= s) bsc += t;
    }
    const int base = __shfl(bsc, blockIdx.x, 64) - __shfl(bv, blockIdx.x, 64);
    const int total = __shfl(bsc, nb - 1, 64);

    int i0 = blockIdx.x * CHUNK + threadIdx.x * 4;
    int d0 = 0, d1 = 0, d2 = 0, d3 = 0;
    if (i0 + 0 < n) d0 = deg[i0 + 0];
    if (i0 + 1 < n) d1 = deg[i0 + 1];
    if (i0 + 2 < n) d2 = deg[i0 + 2];
    if (i0 + 3 < n) d3 = deg[i0 + 3];
    int v0 = (d0 + 3) & ~3, v1 = (d1 + 3) & ~3, v2 = (d2 + 3) & ~3, v3 = (d3 + 3) & ~3;
    int tsum = v0 + v1 + v2 + v3;
    int sc = tsum;
    #pragma unroll
    for (int s = 1; s < 64; s <<= 1) {
        int t = __shfl_up(sc, s, 64);
        if (lane >= s) sc += t;
    }
    if (lane == 63) ws[wv] = sc;
    __syncthreads();
    int woff = 0;
    for (int w = 0; w < wv; ++w) woff += ws[w];
    int p = base + woff + (sc - tsum);
    #define EMIT(idx, dj, vj)                                            \
        if (i0 + idx < n) {                                              \
            off[i0 + idx] = p; cursor[i0 + idx] = p;                     \
            for (int q = p + dj; q < p + vj; ++q) esrc[q] = n;           \
            p += vj;                                                     \
        }
    EMIT(0, d0, v0) EMIT(1, d1, v1) EMIT(2, d2, v2) EMIT(3, d3, v3)
    #undef EMIT
    if (blockIdx.x == 0 && threadIdx.x == 0) off[n] = total;
}

__global__ void fill_kernel(const int* __restrict__ src, const int* __restrict__ dst,
                            int* __restrict__ cursor, int* __restrict__ esrc, int E) {
    int i = blockIdx.x * blockDim.x + threadIdx.x;
    if (i < E) {
        int p = atomicAdd(&cursor[dst[i]], 1);
        esrc[p] = src[i];
    }
}

// ---------- dual GEMM v4: operand-swapped MFMA; za fp8 OR bf16, zb bf16+bias ----
// za = A@Wa^T (fp8 if ZA_FP8 else bf16), zb = bf16(A@Wb^T + bias).
// Block 256 = 4 waves: wave&1 selects output, wave>>1 selects 32-row half.
// D[m=wcol][n=node]: lane owns one node, 4 consecutive cols/tile -> packed store.
template <int NOUT, bool PROBE_A, bool ZA_FP8>
__global__ __launch_bounds__(256)
void gemm_dual_kernel(const void* __restrict__ A,
                      const unsigned short* __restrict__ Wa,
                      const unsigned short* __restrict__ Wb,
                      const unsigned short* __restrict__ bias,
                      void* __restrict__ za, unsigned short* __restrict__ zb,
                      unsigned int* __restrict__ zrow, int zrow_words, int N) {
    if (blockIdx.x == 0 && threadIdx.x < zrow_words) zrow[threadIdx.x] = 0;
    int a16 = 1;
    if (PROBE_A) a16 = wave_probe16(A);

    const int lane = threadIdx.x & 63;
    const int wave = threadIdx.x >> 6;
    const int sel = wave & 1;
    const int m0 = blockIdx.x * 64 + (wave >> 1) * 32;
    if (m0 >= N) return;
    const int lrow = lane & 15;
    const int kg = lane >> 4;
    const unsigned short* W = sel ? Wb : Wa;
    constexpr int NT = NOUT / 16;

    // preload x-fragments for both row tiles (B-operand: n=node, k=kg*8+j)
    bf16x8 xf[2][4];
    #pragma unroll
    for (int rt = 0; rt < 2; ++rt) {
        const int gr = min(m0 + rt * 16 + lrow, N - 1);
        #pragma unroll
        for (int ks = 0; ks < 4; ++ks) {
            const int k0 = ks * 32 + kg * 8;
            if (a16) {
                xf[rt][ks] = *(const bf16x8*)((const unsigned short*)A + (size_t)gr * D_FEAT + k0);
            } else {
                const float* fp = (const float*)A + (size_t)gr * D_FEAT + k0;
                float4 f0 = *(const float4*)fp, f1 = *(const float4*)(fp + 4);
                union { bf16x8 v; unsigned short us[8]; } t;
                t.us[0] = f_to_bf16(f0.x); t.us[1] = f_to_bf16(f0.y);
                t.us[2] = f_to_bf16(f0.z); t.us[3] = f_to_bf16(f0.w);
                t.us[4] = f_to_bf16(f1.x); t.us[5] = f_to_bf16(f1.y);
                t.us[6] = f_to_bf16(f1.z); t.us[7] = f_to_bf16(f1.w);
                xf[rt][ks] = t.v;
            }
        }
    }

    f32x4 acc[2][NT];
    #pragma unroll
    for (int rt = 0; rt < 2; ++rt)
        #pragma unroll
        for (int t = 0; t < NT; ++t) acc[rt][t] = (f32x4){0, 0, 0, 0};

    #pragma unroll
    for (int ks = 0; ks < 4; ++ks) {
        const int k0 = ks * 32 + kg * 8;
        #pragma unroll
        for (int t = 0; t < NT; ++t) {
            bf16x8 wf = *(const bf16x8*)(W + (size_t)(t * 16 + lrow) * D_FEAT + k0);
            acc[0][t] = __builtin_amdgcn_mfma_f32_16x16x32_bf16(wf, xf[0][ks], acc[0][t], 0, 0, 0);
            acc[1][t] = __builtin_amdgcn_mfma_f32_16x16x32_bf16(wf, xf[1][ks], acc[1][t], 0, 0, 0);
        }
    }

    // store: lane owns node = m0+rt*16+lrow, cols t*16+kg*4 .. +3
    #pragma unroll
    for (int rt = 0; rt < 2; ++rt) {
        const int nd = m0 + rt * 16 + lrow;
        if (nd < N) {
            #pragma unroll
            for (int t = 0; t < NT; ++t) {
                const int c0 = t * 16 + kg * 4;
                float v0 = acc[rt][t][0], v1 = acc[rt][t][1];
                float v2 = acc[rt][t][2], v3 = acc[rt][t][3];
                if (sel) {   // zb: bf16 + bias
                    uint2 bb = *(const uint2*)(bias + c0);
                    v0 += bits_to_f(bb.x << 16); v1 += bits_to_f(bb.x & 0xffff0000u);
                    v2 += bits_to_f(bb.y << 16); v3 += bits_to_f(bb.y & 0xffff0000u);
                    unsigned int p0 = (unsigned int)f_to_bf16(v0) | ((unsigned int)f_to_bf16(v1) << 16);
                    unsigned int p1 = (unsigned int)f_to_bf16(v2) | ((unsigned int)f_to_bf16(v3) << 16);
                    *(uint2*)(zb + (size_t)nd * NOUT + c0) = make_uint2(p0, p1);
                } else if (ZA_FP8) {
                    *(unsigned int*)((unsigned char*)za + (size_t)nd * NOUT + c0) =
                        pack4_fp8(v0, v1, v2, v3);
                } else {     // za bf16
                    unsigned int p0 = (unsigned int)f_to_bf16(v0) | ((unsigned int)f_to_bf16(v1) << 16);
                    unsigned int p1 = (unsigned int)f_to_bf16(v2) | ((unsigned int)f_to_bf16(v3) << 16);
                    *(uint2*)((unsigned short*)za + (size_t)nd * NOUT + c0) = make_uint2(p0, p1);
                }
            }
        }
    }
}

// ---------- agg1: h = relu(mean_nb(zl_fp8) + h), D=128; 4 nodes/wave ----------
__global__ __launch_bounds__(256)
void agg1_kernel(const unsigned char* __restrict__ zl,    // (N+1) fp8 rows, row N = 0
                 unsigned short* __restrict__ h,          // in: x@W1r^T+b1; out: result
                 const int* __restrict__ off, const int* __restrict__ deg,
                 const int* __restrict__ esrc, int N) {
    const int lane = threadIdx.x & 63;
    const int wave = threadIdx.x >> 6;
    const int a_lo = (blockIdx.x * 4 + wave) * 4;
    if (a_lo >= N) return;
    const int a_hi = min(a_lo + 4, N);
    const int nn = a_hi - a_lo;
    int offv = off[min(a_lo + min(lane, 4), N)];
    int degv = deg[min(a_lo + min(lane, 3), N - 1)];
    #define OFFAT(i) __shfl(offv, (i), 64)
    const int e_beg = OFFAT(0);
    const int e_end = OFFAT(nn);
    const int quarter = lane >> 4;
    const int fl = lane & 15;        // features fl*8 .. fl*8+7
    float ax[8];
    #pragma unroll
    for (int i = 0; i < 8; ++i) ax[i] = 0.f;
    int g = a_lo;
    int gend = OFFAT(1);

    auto flush = [&](int gg) {
        int td = __shfl(degv, gg - a_lo, 64);
        float inv = 1.f / (float)(td > 0 ? td : 1);
        float v[8];
        #pragma unroll
        for (int i = 0; i < 8; ++i) {
            float s = ax[i];
            s += __shfl_xor(s, 16, 64); s += __shfl_xor(s, 32, 64);
            v[i] = s * inv; ax[i] = 0.f;
        }
        if (quarter == 0) {
            unsigned short* hp = h + (size_t)gg * D_FEAT + fl * 8;
            uint4 zr = *(const uint4*)hp;
            unsigned int w[4] = {zr.x, zr.y, zr.z, zr.w};
            unsigned int pk[4];
            #pragma unroll
            for (int i = 0; i < 4; ++i) {
                float r0 = fmaxf(v[2 * i]     + bits_to_f(w[i] << 16), 0.f);
                float r1 = fmaxf(v[2 * i + 1] + bits_to_f(w[i] & 0xffff0000u), 0.f);
                pk[i] = (unsigned int)f_to_bf16(r0) | ((unsigned int)f_to_bf16(r1) << 16);
            }
            *(uint4*)hp = make_uint4(pk[0], pk[1], pk[2], pk[3]);
        }
    };

    int cur = (e_beg < e_end) ? esrc[min(e_beg + (lane & 31), e_end - 1)] : 0;
    for (int e = e_beg; e < e_end; e += 32) {
        int nxt = (e + 32 < e_end) ? esrc[min(e + 32 + (lane & 31), e_end - 1)] : 0;
        uint2 r[8];
        #pragma unroll
        for (int k = 0; k < 8; ++k) {
            int sk = __shfl(cur, 4 * k + quarter, 64);
            r[k] = *(const uint2*)(zl + (size_t)sk * D_FEAT + fl * 8);
        }
        #pragma unroll
        for (int k = 0; k < 8; ++k) {
            const int eb = e + 4 * k;
            if (eb < e_end) {
                while (eb >= gend) {
                    flush(g); ++g;
                    gend = OFFAT(min(g - a_lo + 1, 4));
                }
                f32x2 p0 = __builtin_amdgcn_cvt_pk_f32_fp8((int)r[k].x, false);
                f32x2 p1 = __builtin_amdgcn_cvt_pk_f32_fp8((int)r[k].x, true);
                f32x2 p2 = __builtin_amdgcn_cvt_pk_f32_fp8((int)r[k].y, false);
                f32x2 p3 = __builtin_amdgcn_cvt_pk_f32_fp8((int)r[k].y, true);
                ax[0] += p0.x; ax[1] += p0.y; ax[2] += p1.x; ax[3] += p1.y;
                ax[4] += p2.x; ax[5] += p2.y; ax[6] += p3.x; ax[7] += p3.y;
            }
        }
        cur = nxt;
    }
    while (g < a_hi) {
        flush(g); ++g;
        gend = OFFAT(min(g - a_lo + 1, 4));
    }
    #undef OFFAT
}

// ---------- agg2: out = mean_nb(z2l_bf16) + s2, D=64; 4 nodes/wave ----------
__global__ __launch_bounds__(256)
void agg2_kernel(const unsigned short* __restrict__ z2l,  // (N+1) bf16 rows, row N = 0
                 const unsigned short* __restrict__ s2,
                 void* __restrict__ out, const void* __restrict__ x,
                 const int* __restrict__ off, const int* __restrict__ deg,
                 const int* __restrict__ esrc, int N) {
    const int o16 = wave_probe16(x);
    const int lane = threadIdx.x & 63;
    const int wave = threadIdx.x >> 6;
    const int a_lo = (blockIdx.x * 4 + wave) * 4;
    if (a_lo >= N) return;
    const int a_hi = min(a_lo + 4, N);
    const int nn = a_hi - a_lo;
    int offv = off[min(a_lo + min(lane, 4), N)];
    int degv = deg[min(a_lo + min(lane, 3), N - 1)];
    #define OFFAT(i) __shfl(offv, (i), 64)
    const int e_beg = OFFAT(0);
    const int e_end = OFFAT(nn);
    const int quarter = lane >> 4;
    const int fl = lane & 15;        // features fl*4 .. fl*4+3
    float ax[4];
    #pragma unroll
    for (int i = 0; i < 4; ++i) ax[i] = 0.f;
    int g = a_lo;
    int gend = OFFAT(1);

    auto flush = [&](int gg) {
        int td = __shfl(degv, gg - a_lo, 64);
        float inv = 1.f / (float)(td > 0 ? td : 1);
        float v[4];
        #pragma unroll
        for (int i = 0; i < 4; ++i) {
            float s = ax[i];
            s += __shfl_xor(s, 16, 64); s += __shfl_xor(s, 32, 64);
            v[i] = s * inv; ax[i] = 0.f;
        }
        if (quarter == 0) {
            uint2 sb = *(const uint2*)(s2 + (size_t)gg * 64 + fl * 4);
            v[0] += bits_to_f(sb.x << 16); v[1] += bits_to_f(sb.x & 0xffff0000u);
            v[2] += bits_to_f(sb.y << 16); v[3] += bits_to_f(sb.y & 0xffff0000u);
            if (o16) {
                unsigned int p0 = (unsigned int)f_to_bf16(v[0]) | ((unsigned int)f_to_bf16(v[1]) << 16);
                unsigned int p1 = (unsigned int)f_to_bf16(v[2]) | ((unsigned int)f_to_bf16(v[3]) << 16);
                *(uint2*)((unsigned short*)out + (size_t)gg * 64 + fl * 4) = make_uint2(p0, p1);
            } else {
                *(float4*)((float*)out + (size_t)gg * 64 + fl * 4) =
                    make_float4(v[0], v[1], v[2], v[3]);
            }
        }
    };

    int cur = (e_beg < e_end) ? esrc[min(e_beg + (lane & 31), e_end - 1)] : 0;
    for (int e = e_beg; e < e_end; e += 32) {
        int nxt = (e + 32 < e_end) ? esrc[min(e + 32 + (lane & 31), e_end - 1)] : 0;
        uint2 r[8];
        #pragma unroll
        for (int k = 0; k < 8; ++k) {
            int sk = __shfl(cur, 4 * k + quarter, 64);
            r[k] = *(const uint2*)(z2l + (size_t)sk * 64 + fl * 4);
        }
        #pragma unroll
        for (int k = 0; k < 8; ++k) {
            const int eb = e + 4 * k;
            if (eb < e_end) {
                while (eb >= gend) {
                    flush(g); ++g;
                    gend = OFFAT(min(g - a_lo + 1, 4));
                }
                uint2 u = r[k];
                ax[0] += bits_to_f(u.x << 16); ax[1] += bits_to_f(u.x & 0xffff0000u);
                ax[2] += bits_to_f(u.y << 16); ax[3] += bits_to_f(u.y & 0xffff0000u);
            }
        }
        cur = nxt;
    }
    while (g < a_hi) {
        flush(g); ++g;
        gend = OFFAT(min(g - a_lo + 1, 4));
    }
    #undef OFFAT
}

// ---------- launch ----------
extern "C" void kernel_launch(void* const* d_in, const int* in_sizes, int n_in,
                              void* d_out, int out_size, void* d_ws, size_t ws_size,
                              hipStream_t stream) {
    const void* x   = d_in[0];
    const int* eidx = (const int*)d_in[1];
    const void* W1l = d_in[2];
    const void* b1  = d_in[3];
    const void* W1r = d_in[4];
    const void* W2l = d_in[5];
    const void* b2  = d_in[6];
    const void* W2r = d_in[7];

    const int N = in_sizes[0] / D_FEAT;   // 50000
    const int E = in_sizes[1] / 2;        // 600000
    const int* src = eidx;                // [2, E] row-major (proven R5)
    const int* dst = eidx + E;

    char* ws = (char*)d_ws;
    size_t o = 0;
    auto alloc = [&](size_t bytes) -> void* {
        void* p = ws + o;
        o += (bytes + 255) & ~(size_t)255;
        return p;
    };
    int* deg    = (int*)alloc((size_t)N * 4);
    int* off    = (int*)alloc((size_t)(N + 1) * 4);
    int* cursor = (int*)alloc((size_t)N * 4);
    int* bsum   = (int*)alloc(64 * 4);
    int* esrc   = (int*)alloc((size_t)(E + 3 * N + 64) * 4);
    unsigned short* wconv = (unsigned short*)alloc(NW * 2);
    unsigned char*  zl = (unsigned char*)alloc((size_t)(N + 1) * D_FEAT);      // 6.4 MB fp8
    unsigned short* h  = (unsigned short*)alloc((size_t)N * D_FEAT * 2);       // 12.8 MB
    unsigned short* s2 = (unsigned short*)alloc((size_t)N * 64 * 2);           // 6.4 MB
    // z2l (bf16, (N+1)x64 = 6.4 MB) aliases the dead zl region (6.4 MB) exactly
    unsigned short* z2l = (unsigned short*)zl;
    (void)n_in; (void)out_size; (void)ws_size;   // ~28.9 MB total (proven R8-R11)

    hipMemsetAsync(deg, 0, (size_t)N * 4, stream);
    setup_kernel<<<(NW + E + 255) / 256, 256, 0, stream>>>(
        x, W1l, b1, W1r, W2l, b2, W2r, dst, E, wconv, deg);
    const int nchunk = (N + CHUNK - 1) / CHUNK;   // 49 <= 64
    scan1_kernel<<<nchunk, 256, 0, stream>>>(deg, bsum, N);
    scan3_kernel<<<nchunk, 256, 0, stream>>>(deg, bsum, nchunk, off, cursor, esrc, N);
    fill_kernel<<<(E + 255) / 256, 256, 0, stream>>>(src, dst, cursor, esrc, E);

    const int gblocks = (N + 63) / 64;    // 782
    const int ablocks = (N + 15) / 16;    // 3125 (4 nodes/wave, 4 waves/block)
    // layer 1: zl = fp8(x@W1l^T), h = x@W1r^T + b1; then h = relu(mean(zl)+h)
    gemm_dual_kernel<128, true, true><<<gblocks, 256, 0, stream>>>(
        x, wconv + 0, wconv + 16384, wconv + 49152,
        zl, h, (unsigned int*)(zl + (size_t)N * D_FEAT), 32, N);
    agg1_kernel<<<ablocks, 256, 0, stream>>>(zl, h, off, deg, esrc, N);
    // layer 2: z2l = bf16(h@W2l^T), s2 = h@W2r^T + b2; then out = mean(z2l)+s2
    gemm_dual_kernel<64, false, false><<<gblocks, 256, 0, stream>>>(
        h, wconv + 32768, wconv + 40960, wconv + 49280,
        z2l, s2, (unsigned int*)(z2l + (size_t)N * 64), 32, N);
    agg2_kernel<<<ablocks, 256, 0, stream>>>(z2l, s2, d_out, x, off, deg, esrc, N);
}

// Round 13
// 228.855 us; speedup vs baseline: 1.0521x; 1.0521x over previous
//
#include <hip/hip_runtime.h>
#include <hip/hip_bf16.h>

typedef __bf16 bf16x8 __attribute__((ext_vector_type(8)));
typedef float f32x4 __attribute__((ext_vector_type(4)));
typedef float f32x2 __attribute__((ext_vector_type(2)));

#define D_FEAT 128
#define CHUNK 1024
#define NW 49344   // packed weight elements

__device__ __forceinline__ float bits_to_f(unsigned int u) {
    union { unsigned int i; float f; } c; c.i = u; return c.f;
}
__device__ __forceinline__ unsigned short f_to_bf16(float f) {
    __hip_bfloat16 h = (__hip_bfloat16)f;
    return *(unsigned short*)&h;
}
__device__ __forceinline__ float ld(const void* p, int is16, size_t i) {
    return is16 ? (float)((const __hip_bfloat16*)p)[i] : ((const float*)p)[i];
}
// pack 4 floats -> 4 fp8 e4m3 (bytes 0..3), HW RNE
__device__ __forceinline__ unsigned int pack4_fp8(float v0, float v1, float v2, float v3) {
    int w = __builtin_amdgcn_cvt_pk_fp8_f32(v0, v1, 0, false);
    w = __builtin_amdgcn_cvt_pk_fp8_f32(v2, v3, w, true);
    return (unsigned int)w;
}
// per-wave dtype probe (proven R5-R12)
__device__ __forceinline__ int wave_probe16(const void* p) {
    const unsigned short v = ((const unsigned short*)p)[(threadIdx.x & 63) * 2];
    int e = (v >> 7) & 0xFF;
    unsigned long long m = __ballot(e >= 100 && e <= 140);
    return (__popcll(m) >= 48) ? 1 : 0;
}

// ---------- setup: weight pack -> bf16 AND degree count, one dispatch ----------
__global__ void setup_kernel(const void* x,
                             const void* W1l, const void* b1, const void* W1r,
                             const void* W2l, const void* b2, const void* W2r,
                             const int* __restrict__ dst, int E,
                             unsigned short* __restrict__ wout, int* __restrict__ deg) {
    int i = blockIdx.x * blockDim.x + threadIdx.x;
    if (i < NW) {            // 771 full waves; no wave straddles the boundary
        int is16 = wave_probe16(x);
        const void* s; int base;
        if      (i < 16384) { s = W1l; base = 0; }
        else if (i < 32768) { s = W1r; base = 16384; }
        else if (i < 40960) { s = W2l; base = 32768; }
        else if (i < 49152) { s = W2r; base = 40960; }
        else if (i < 49280) { s = b1;  base = 49152; }
        else                { s = b2;  base = 49280; }
        wout[i] = f_to_bf16(ld(s, is16, i - base));
    } else {
        int j = i - NW;
        if (j < E) atomicAdd(&deg[dst[j]], 1);
    }
}

// ---------- scan phase 1: per-chunk padded-degree sums ----------
__global__ void scan1_kernel(const int* __restrict__ deg, int* __restrict__ bsum, int n) {
    __shared__ int ws[4];
    const int lane = threadIdx.x & 63, wv = threadIdx.x >> 6;
    int i0 = blockIdx.x * CHUNK + threadIdx.x * 4;
    int s = 0;
    #pragma unroll
    for (int j = 0; j < 4; ++j)
        if (i0 + j < n) { int d = deg[i0 + j]; s += (d + 3) & ~3; }
    #pragma unroll
    for (int d = 1; d < 64; d <<= 1) s += __shfl_xor(s, d, 64);
    if (lane == 0) ws[wv] = s;
    __syncthreads();
    if (threadIdx.x == 0) bsum[blockIdx.x] = ws[0] + ws[1] + ws[2] + ws[3];
}

// ---------- scan phase 2 (merged scan2+scan3+pad writes) ----------
__global__ void scan3_kernel(const int* __restrict__ deg, const int* __restrict__ bsum,
                             int nb, int* __restrict__ off, int* __restrict__ cursor,
                             int* __restrict__ esrc, int n) {
    __shared__ int ws[4];
    const int lane = threadIdx.x & 63, wv = threadIdx.x >> 6;
    int bv = (lane < nb) ? bsum[lane] : 0;
    int bsc = bv;
    #pragma unroll
    for (int s = 1; s < 64; s <<= 1) {
        int t = __shfl_up(bsc, s, 64);
        if (lane >= s) bsc += t;
    }
    const int base = __shfl(bsc, blockIdx.x, 64) - __shfl(bv, blockIdx.x, 64);
    const int total = __shfl(bsc, nb - 1, 64);

    int i0 = blockIdx.x * CHUNK + threadIdx.x * 4;
    int d0 = 0, d1 = 0, d2 = 0, d3 = 0;
    if (i0 + 0 < n) d0 = deg[i0 + 0];
    if (i0 + 1 < n) d1 = deg[i0 + 1];
    if (i0 + 2 < n) d2 = deg[i0 + 2];
    if (i0 + 3 < n) d3 = deg[i0 + 3];
    int v0 = (d0 + 3) & ~3, v1 = (d1 + 3) & ~3, v2 = (d2 + 3) & ~3, v3 = (d3 + 3) & ~3;
    int tsum = v0 + v1 + v2 + v3;
    int sc = tsum;
    #pragma unroll
    for (int s = 1; s < 64; s <<= 1) {
        int t = __shfl_up(sc, s, 64);
        if (lane >= s) sc += t;
    }
    if (lane == 63) ws[wv] = sc;
    __syncthreads();
    int woff = 0;
    for (int w = 0; w < wv; ++w) woff += ws[w];
    int p = base + woff + (sc - tsum);
    #define EMIT(idx, dj, vj)                                            \
        if (i0 + idx < n) {                                              \
            off[i0 + idx] = p; cursor[i0 + idx] = p;                     \
            for (int q = p + dj; q < p + vj; ++q) esrc[q] = n;           \
            p += vj;                                                     \
        }
    EMIT(0, d0, v0) EMIT(1, d1, v1) EMIT(2, d2, v2) EMIT(3, d3, v3)
    #undef EMIT
    if (blockIdx.x == 0 && threadIdx.x == 0) off[n] = total;
}

__global__ void fill_kernel(const int* __restrict__ src, const int* __restrict__ dst,
                            int* __restrict__ cursor, int* __restrict__ esrc, int E) {
    int i = blockIdx.x * blockDim.x + threadIdx.x;
    if (i < E) {
        int p = atomicAdd(&cursor[dst[i]], 1);
        esrc[p] = src[i];
    }
}

// ---------- layer-1 dual GEMM: zl = fp8(x@W1l^T), h = bf16(x@W1r^T + b1) ----------
// Operand-swapped MFMA (proven R10-R12). Block 256 = 4 waves: wave&1 selects
// output, wave>>1 selects 32-row half. Lane owns one node, 4 cols/tile packed.
__global__ __launch_bounds__(256)
void gemm1_kernel(const void* __restrict__ A,
                  const unsigned short* __restrict__ Wa,
                  const unsigned short* __restrict__ Wb,
                  const unsigned short* __restrict__ bias,
                  unsigned char* __restrict__ za, unsigned short* __restrict__ zb,
                  unsigned int* __restrict__ zrow, int zrow_words, int N) {
    if (blockIdx.x == 0 && threadIdx.x < zrow_words) zrow[threadIdx.x] = 0;
    const int a16 = wave_probe16(A);

    const int lane = threadIdx.x & 63;
    const int wave = threadIdx.x >> 6;
    const int sel = wave & 1;
    const int m0 = blockIdx.x * 64 + (wave >> 1) * 32;
    if (m0 >= N) return;
    const int lrow = lane & 15;
    const int kg = lane >> 4;
    const unsigned short* W = sel ? Wb : Wa;
    constexpr int NT = 8;   // 128/16

    bf16x8 xf[2][4];
    #pragma unroll
    for (int rt = 0; rt < 2; ++rt) {
        const int gr = min(m0 + rt * 16 + lrow, N - 1);
        #pragma unroll
        for (int ks = 0; ks < 4; ++ks) {
            const int k0 = ks * 32 + kg * 8;
            if (a16) {
                xf[rt][ks] = *(const bf16x8*)((const unsigned short*)A + (size_t)gr * D_FEAT + k0);
            } else {
                const float* fp = (const float*)A + (size_t)gr * D_FEAT + k0;
                float4 f0 = *(const float4*)fp, f1 = *(const float4*)(fp + 4);
                union { bf16x8 v; unsigned short us[8]; } t;
                t.us[0] = f_to_bf16(f0.x); t.us[1] = f_to_bf16(f0.y);
                t.us[2] = f_to_bf16(f0.z); t.us[3] = f_to_bf16(f0.w);
                t.us[4] = f_to_bf16(f1.x); t.us[5] = f_to_bf16(f1.y);
                t.us[6] = f_to_bf16(f1.z); t.us[7] = f_to_bf16(f1.w);
                xf[rt][ks] = t.v;
            }
        }
    }

    f32x4 acc[2][NT];
    #pragma unroll
    for (int rt = 0; rt < 2; ++rt)
        #pragma unroll
        for (int t = 0; t < NT; ++t) acc[rt][t] = (f32x4){0, 0, 0, 0};

    #pragma unroll
    for (int ks = 0; ks < 4; ++ks) {
        const int k0 = ks * 32 + kg * 8;
        #pragma unroll
        for (int t = 0; t < NT; ++t) {
            bf16x8 wf = *(const bf16x8*)(W + (size_t)(t * 16 + lrow) * D_FEAT + k0);
            acc[0][t] = __builtin_amdgcn_mfma_f32_16x16x32_bf16(wf, xf[0][ks], acc[0][t], 0, 0, 0);
            acc[1][t] = __builtin_amdgcn_mfma_f32_16x16x32_bf16(wf, xf[1][ks], acc[1][t], 0, 0, 0);
        }
    }

    #pragma unroll
    for (int rt = 0; rt < 2; ++rt) {
        const int nd = m0 + rt * 16 + lrow;
        if (nd < N) {
            #pragma unroll
            for (int t = 0; t < NT; ++t) {
                const int c0 = t * 16 + kg * 4;
                float v0 = acc[rt][t][0], v1 = acc[rt][t][1];
                float v2 = acc[rt][t][2], v3 = acc[rt][t][3];
                if (sel) {   // zb: bf16 + bias
                    uint2 bb = *(const uint2*)(bias + c0);
                    v0 += bits_to_f(bb.x << 16); v1 += bits_to_f(bb.x & 0xffff0000u);
                    v2 += bits_to_f(bb.y << 16); v3 += bits_to_f(bb.y & 0xffff0000u);
                    unsigned int p0 = (unsigned int)f_to_bf16(v0) | ((unsigned int)f_to_bf16(v1) << 16);
                    unsigned int p1 = (unsigned int)f_to_bf16(v2) | ((unsigned int)f_to_bf16(v3) << 16);
                    *(uint2*)(zb + (size_t)nd * D_FEAT + c0) = make_uint2(p0, p1);
                } else {     // za: fp8
                    *(unsigned int*)(za + (size_t)nd * D_FEAT + c0) = pack4_fp8(v0, v1, v2, v3);
                }
            }
        }
    }
}

// ---------- fused agg1 + gemm2: per 16-node block ----------
// Phase A (per wave, 4 nodes): hrow = relu(mean_nb(zl_fp8) + h_in) -> LDS tile.
// Phase B (whole block): [z2l | s2] = [hrow@W2l^T | hrow@W2r^T + b2] stored
// interleaved back into h's own rows (cols 0..63 / 64..127). Safe aliasing:
// a block only overwrites rows whose h_in it already consumed; no cross-block reads.
__global__ __launch_bounds__(256)
void agg1g2_kernel(const unsigned char* __restrict__ zl,   // (N+1) fp8 rows, row N = 0
                   unsigned short* __restrict__ h,         // in: x@W1r^T+b1; out: z2l|s2
                   const unsigned short* __restrict__ W2l,
                   const unsigned short* __restrict__ W2r,
                   const unsigned short* __restrict__ b2,
                   const int* __restrict__ off, const int* __restrict__ deg,
                   const int* __restrict__ esrc, int N) {
    __shared__ unsigned short ht[16][136];   // +8 pad: row stride 272 B
    const int tid = threadIdx.x;
    const int lane = tid & 63;
    const int wave = tid >> 6;
    const int nb0 = blockIdx.x * 16;
    if (nb0 >= N) return;   // block-uniform

    // zero LDS (tail rows must not feed NaN into MFMA) + z2l dummy row N
    for (int i = tid; i < 16 * 136 / 2; i += 256) ((unsigned int*)ht)[i] = 0;
    if (blockIdx.x == 0 && tid < 32) ((unsigned int*)(h + (size_t)N * D_FEAT))[tid] = 0;
    __syncthreads();

    // ---- phase A: aggregation, 4 nodes per wave (R11/R12-proven loop) ----
    const int a_lo = nb0 + wave * 4;
    if (a_lo < N) {
        const int a_hi = min(a_lo + 4, N);
        const int nn = a_hi - a_lo;
        int offv = off[min(a_lo + min(lane, 4), N)];
        int degv = deg[min(a_lo + min(lane, 3), N - 1)];
        #define OFFAT(i) __shfl(offv, (i), 64)
        const int e_beg = OFFAT(0);
        const int e_end = OFFAT(nn);
        const int quarter = lane >> 4;
        const int fl = lane & 15;        // features fl*8 .. fl*8+7
        float ax[8];
        #pragma unroll
        for (int i = 0; i < 8; ++i) ax[i] = 0.f;
        int g = a_lo;
        int gend = OFFAT(1);

        auto flush = [&](int gg) {
            int td = __shfl(degv, gg - a_lo, 64);
            float inv = 1.f / (float)(td > 0 ? td : 1);
            float v[8];
            #pragma unroll
            for (int i = 0; i < 8; ++i) {
                float s = ax[i];
                s += __shfl_xor(s, 16, 64); s += __shfl_xor(s, 32, 64);
                v[i] = s * inv; ax[i] = 0.f;
            }
            if (quarter == 0) {
                const unsigned short* hp = h + (size_t)gg * D_FEAT + fl * 8;
                uint4 zr = *(const uint4*)hp;
                unsigned int w[4] = {zr.x, zr.y, zr.z, zr.w};
                unsigned int pk[4];
                #pragma unroll
                for (int i = 0; i < 4; ++i) {
                    float r0 = fmaxf(v[2 * i]     + bits_to_f(w[i] << 16), 0.f);
                    float r1 = fmaxf(v[2 * i + 1] + bits_to_f(w[i] & 0xffff0000u), 0.f);
                    pk[i] = (unsigned int)f_to_bf16(r0) | ((unsigned int)f_to_bf16(r1) << 16);
                }
                *(uint4*)&ht[gg - nb0][fl * 8] = make_uint4(pk[0], pk[1], pk[2], pk[3]);
            }
        };

        int cur = (e_beg < e_end) ? esrc[min(e_beg + (lane & 31), e_end - 1)] : 0;
        for (int e = e_beg; e < e_end; e += 32) {
            int nxt = (e + 32 < e_end) ? esrc[min(e + 32 + (lane & 31), e_end - 1)] : 0;
            uint2 r[8];
            #pragma unroll
            for (int k = 0; k < 8; ++k) {
                int sk = __shfl(cur, 4 * k + quarter, 64);
                r[k] = *(const uint2*)(zl + (size_t)sk * D_FEAT + fl * 8);
            }
            #pragma unroll
            for (int k = 0; k < 8; ++k) {
                const int eb = e + 4 * k;
                if (eb < e_end) {
                    while (eb >= gend) {
                        flush(g); ++g;
                        gend = OFFAT(min(g - a_lo + 1, 4));
                    }
                    f32x2 p0 = __builtin_amdgcn_cvt_pk_f32_fp8((int)r[k].x, false);
                    f32x2 p1 = __builtin_amdgcn_cvt_pk_f32_fp8((int)r[k].x, true);
                    f32x2 p2 = __builtin_amdgcn_cvt_pk_f32_fp8((int)r[k].y, false);
                    f32x2 p3 = __builtin_amdgcn_cvt_pk_f32_fp8((int)r[k].y, true);
                    ax[0] += p0.x; ax[1] += p0.y; ax[2] += p1.x; ax[3] += p1.y;
                    ax[4] += p2.x; ax[5] += p2.y; ax[6] += p3.x; ax[7] += p3.y;
                }
            }
            cur = nxt;
        }
        while (g < a_hi) {
            flush(g); ++g;
            gend = OFFAT(min(g - a_lo + 1, 4));
        }
        #undef OFFAT
    }
    __syncthreads();

    // ---- phase B: dual GEMM on this block's 16 h-rows (from LDS) ----
    // wave covers combined cols [wave*32, wave*32+32): 2 tiles of 16.
    const int lrow = lane & 15;
    const int kg = lane >> 4;
    const int node = nb0 + lrow;
    f32x4 acc[2];
    acc[0] = (f32x4){0, 0, 0, 0};
    acc[1] = (f32x4){0, 0, 0, 0};
    #pragma unroll
    for (int ks = 0; ks < 4; ++ks) {
        const int k0 = ks * 32 + kg * 8;
        bf16x8 xf = *(const bf16x8*)&ht[lrow][k0];
        #pragma unroll
        for (int t = 0; t < 2; ++t) {
            const int cb = wave * 32 + t * 16;   // tile base col in [0,128)
            const unsigned short* W = (cb < 64) ? W2l : W2r;
            const int wrow = ((cb < 64) ? cb : cb - 64) + lrow;
            bf16x8 wf = *(const bf16x8*)(W + (size_t)wrow * D_FEAT + k0);
            acc[t] = __builtin_amdgcn_mfma_f32_16x16x32_bf16(wf, xf, acc[t], 0, 0, 0);
        }
    }
    if (node < N) {
        #pragma unroll
        for (int t = 0; t < 2; ++t) {
            const int cb = wave * 32 + t * 16;
            const int cc0 = cb + kg * 4;
            float v0 = acc[t][0], v1 = acc[t][1], v2 = acc[t][2], v3 = acc[t][3];
            if (cb >= 64) {   // s2 half: add bias
                uint2 bb = *(const uint2*)(b2 + (cc0 - 64));
                v0 += bits_to_f(bb.x << 16); v1 += bits_to_f(bb.x & 0xffff0000u);
                v2 += bits_to_f(bb.y << 16); v3 += bits_to_f(bb.y & 0xffff0000u);
            }
            unsigned int p0 = (unsigned int)f_to_bf16(v0) | ((unsigned int)f_to_bf16(v1) << 16);
            unsigned int p1 = (unsigned int)f_to_bf16(v2) | ((unsigned int)f_to_bf16(v3) << 16);
            *(uint2*)(h + (size_t)node * D_FEAT + cc0) = make_uint2(p0, p1);
        }
    }
}

// ---------- agg2: out = mean_nb(z2l) + s2; z2s rows = [z2l(64) | s2(64)] ----------
__global__ __launch_bounds__(256)
void agg2_kernel(const unsigned short* __restrict__ z2s,  // (N+1) rows x 128; row N cols 0..63 = 0
                 void* __restrict__ out, const void* __restrict__ x,
                 const int* __restrict__ off, const int* __restrict__ deg,
                 const int* __restrict__ esrc, int N) {
    const int o16 = wave_probe16(x);
    const int lane = threadIdx.x & 63;
    const int wave = threadIdx.x >> 6;
    const int a_lo = (blockIdx.x * 4 + wave) * 4;
    if (a_lo >= N) return;
    const int a_hi = min(a_lo + 4, N);
    const int nn = a_hi - a_lo;
    int offv = off[min(a_lo + min(lane, 4), N)];
    int degv = deg[min(a_lo + min(lane, 3), N - 1)];
    #define OFFAT(i) __shfl(offv, (i), 64)
    const int e_beg = OFFAT(0);
    const int e_end = OFFAT(nn);
    const int quarter = lane >> 4;
    const int fl = lane & 15;        // features fl*4 .. fl*4+3
    float ax[4];
    #pragma unroll
    for (int i = 0; i < 4; ++i) ax[i] = 0.f;
    int g = a_lo;
    int gend = OFFAT(1);

    auto flush = [&](int gg) {
        int td = __shfl(degv, gg - a_lo, 64);
        float inv = 1.f / (float)(td > 0 ? td : 1);
        float v[4];
        #pragma unroll
        for (int i = 0; i < 4; ++i) {
            float s = ax[i];
            s += __shfl_xor(s, 16, 64); s += __shfl_xor(s, 32, 64);
            v[i] = s * inv; ax[i] = 0.f;
        }
        if (quarter == 0) {
            uint2 sb = *(const uint2*)(z2s + (size_t)gg * D_FEAT + 64 + fl * 4);
            v[0] += bits_to_f(sb.x << 16); v[1] += bits_to_f(sb.x & 0xffff0000u);
            v[2] += bits_to_f(sb.y << 16); v[3] += bits_to_f(sb.y & 0xffff0000u);
            if (o16) {
                unsigned int p0 = (unsigned int)f_to_bf16(v[0]) | ((unsigned int)f_to_bf16(v[1]) << 16);
                unsigned int p1 = (unsigned int)f_to_bf16(v[2]) | ((unsigned int)f_to_bf16(v[3]) << 16);
                *(uint2*)((unsigned short*)out + (size_t)gg * 64 + fl * 4) = make_uint2(p0, p1);
            } else {
                *(float4*)((float*)out + (size_t)gg * 64 + fl * 4) =
                    make_float4(v[0], v[1], v[2], v[3]);
            }
        }
    };

    int cur = (e_beg < e_end) ? esrc[min(e_beg + (lane & 31), e_end - 1)] : 0;
    for (int e = e_beg; e < e_end; e += 32) {
        int nxt = (e + 32 < e_end) ? esrc[min(e + 32 + (lane & 31), e_end - 1)] : 0;
        uint2 r[8];
        #pragma unroll
        for (int k = 0; k < 8; ++k) {
            int sk = __shfl(cur, 4 * k + quarter, 64);
            r[k] = *(const uint2*)(z2s + (size_t)sk * D_FEAT + fl * 4);
        }
        #pragma unroll
        for (int k = 0; k < 8; ++k) {
            const int eb = e + 4 * k;
            if (eb < e_end) {
                while (eb >= gend) {
                    flush(g); ++g;
                    gend = OFFAT(min(g - a_lo + 1, 4));
                }
                uint2 u = r[k];
                ax[0] += bits_to_f(u.x << 16); ax[1] += bits_to_f(u.x & 0xffff0000u);
                ax[2] += bits_to_f(u.y << 16); ax[3] += bits_to_f(u.y & 0xffff0000u);
            }
        }
        cur = nxt;
    }
    while (g < a_hi) {
        flush(g); ++g;
        gend = OFFAT(min(g - a_lo + 1, 4));
    }
    #undef OFFAT
}

// ---------- launch ----------
extern "C" void kernel_launch(void* const* d_in, const int* in_sizes, int n_in,
                              void* d_out, int out_size, void* d_ws, size_t ws_size,
                              hipStream_t stream) {
    const void* x   = d_in[0];
    const int* eidx = (const int*)d_in[1];
    const void* W1l = d_in[2];
    const void* b1  = d_in[3];
    const void* W1r = d_in[4];
    const void* W2l = d_in[5];
    const void* b2  = d_in[6];
    const void* W2r = d_in[7];

    const int N = in_sizes[0] / D_FEAT;   // 50000
    const int E = in_sizes[1] / 2;        // 600000
    const int* src = eidx;                // [2, E] row-major (proven R5)
    const int* dst = eidx + E;

    char* ws = (char*)d_ws;
    size_t o = 0;
    auto alloc = [&](size_t bytes) -> void* {
        void* p = ws + o;
        o += (bytes + 255) & ~(size_t)255;
        return p;
    };
    int* deg    = (int*)alloc((size_t)N * 4);
    int* off    = (int*)alloc((size_t)(N + 1) * 4);
    int* cursor = (int*)alloc((size_t)N * 4);
    int* bsum   = (int*)alloc(64 * 4);
    int* esrc   = (int*)alloc((size_t)(E + 3 * N + 64) * 4);
    unsigned short* wconv = (unsigned short*)alloc(NW * 2);
    unsigned char*  zl = (unsigned char*)alloc((size_t)(N + 1) * D_FEAT);       // 6.4 MB fp8
    unsigned short* h  = (unsigned short*)alloc((size_t)(N + 1) * D_FEAT * 2);  // 12.8 MB
    (void)n_in; (void)out_size; (void)ws_size;   // ~22.5 MB total (29.4 proven)

    hipMemsetAsync(deg, 0, (size_t)N * 4, stream);
    setup_kernel<<<(NW + E + 255) / 256, 256, 0, stream>>>(
        x, W1l, b1, W1r, W2l, b2, W2r, dst, E, wconv, deg);
    const int nchunk = (N + CHUNK - 1) / CHUNK;   // 49 <= 64
    scan1_kernel<<<nchunk, 256, 0, stream>>>(deg, bsum, N);
    scan3_kernel<<<nchunk, 256, 0, stream>>>(deg, bsum, nchunk, off, cursor, esrc, N);
    fill_kernel<<<(E + 255) / 256, 256, 0, stream>>>(src, dst, cursor, esrc, E);

    const int gblocks = (N + 63) / 64;    // 782
    const int fblocks = (N + 15) / 16;    // 3125 (fused agg1+gemm2: 16 nodes/block)
    const int ablocks = (N + 15) / 16;    // 3125 (agg2: 4 nodes/wave)
    // layer 1 GEMM: zl = fp8(x@W1l^T), h = x@W1r^T + b1
    gemm1_kernel<<<gblocks, 256, 0, stream>>>(
        x, wconv + 0, wconv + 16384, wconv + 49152,
        zl, h, (unsigned int*)(zl + (size_t)N * D_FEAT), 32, N);
    // fused: h_rows = relu(mean(zl)+h) [LDS]; h <- [z2l | s2] = [hr@W2l^T | hr@W2r^T+b2]
    agg1g2_kernel<<<fblocks, 256, 0, stream>>>(
        zl, h, wconv + 32768, wconv + 40960, wconv + 49280, off, deg, esrc, N);
    // layer 2 aggregation: out = mean(z2l) + s2
    agg2_kernel<<<ablocks, 256, 0, stream>>>(h, d_out, x, off, deg, esrc, N);
}